// Round 5
// baseline (484.392 us; speedup 1.0000x reference)
//
#include <hip/hip_runtime.h>

typedef short short8 __attribute__((ext_vector_type(8)));
typedef float f32x4 __attribute__((ext_vector_type(4)));

#define B_ROWS 16384
#define SCALE 1.4285714285714286f   // f32 round of 1/0.7, same as np

__device__ __forceinline__ float bf2f(unsigned short u) {
    return __uint_as_float(((unsigned)u) << 16);
}
__device__ __forceinline__ unsigned short f2bf(float f) {
    unsigned u = __float_as_uint(f);
    u += 0x7fffu + ((u >> 16) & 1u);   // RNE
    return (unsigned short)(u >> 16);
}

__device__ __forceinline__ void gl_lds16(const void* g, void* l) {
    __builtin_amdgcn_global_load_lds(
        (const __attribute__((address_space(1))) unsigned int*)g,
        (__attribute__((address_space(3))) unsigned int*)l, 16, 0, 0);
}

__device__ __forceinline__ float wave_max(float v) {
    #pragma unroll
    for (int m = 1; m < 64; m <<= 1) v = fmaxf(v, __shfl_xor(v, m, 64));
    return v;
}
__device__ __forceinline__ float wave_sum(float v) {
    #pragma unroll
    for (int m = 1; m < 64; m <<= 1) v += __shfl_xor(v, m, 64);
    return v;
}

// ---- prep: W1 f32 (4096x128) -> transposed bf16 hi/lo splits (128x4096) ----
__global__ void k_prep(const float* __restrict__ w1,
                       unsigned short* __restrict__ w1h,
                       unsigned short* __restrict__ w1l) {
    int tid = blockIdx.x * 256 + threadIdx.x;     // 524288 total
    int n = tid >> 12, k = tid & 4095;
    float v = w1[k * 128 + n];
    unsigned short hi = f2bf(v);
    w1h[tid] = hi;
    w1l[tid] = f2bf(v - bf2f(hi));
}

// ---- fused: GEMM1 + logits + stats. M=64 rows/block, 256 blocks (1/CU).
// Each wave owns a 32x32 output tile (rg = w>>2 row-half, cg = w&3 col-quad):
// per K-iter/wave 16 ds_read_b128 : 24 MFMA (was 12:12 at M=32) -> 3x less
// LDS-read traffic per output row. Math order bit-identical to R4.
// LDS map (131072 B):
//   phase1: sAh[0:16K) sAl[16K:32K) sBh[32K:64K) sBl[64K:96K)
//   phase2: hbuf[0:32K) hmb[32K:96K) w2s[96K:128K)
//   phase2 tail/phase3: lgs[32K:112K)  (aliases hmb+w2s, barrier-guarded)
__global__ __launch_bounds__(512, 2) void k_fused(
        const float* __restrict__ x,
        const unsigned short* __restrict__ w1h,
        const unsigned short* __restrict__ w1l,
        const float* __restrict__ b1,
        const float* __restrict__ w2,
        const float* __restrict__ b2,
        const float* __restrict__ m1,
        const float* __restrict__ m2,
        float* __restrict__ out) {
    __shared__ __attribute__((aligned(128))) char smem[131072];
    unsigned short* sAh0 = (unsigned short*)smem;             // [2][64*64] 16 KB
    unsigned short* sAl0 = (unsigned short*)(smem + 16384);   //            16 KB
    unsigned short* sBh0 = (unsigned short*)(smem + 32768);   // [2][128*64] 32 KB
    unsigned short* sBl0 = (unsigned short*)(smem + 65536);   //             32 KB
    float* hbuf = (float*)smem;                               // 64x128 f32, 32 KB
    float* hmb  = (float*)(smem + 32768);                     // [2][64*128] 64 KB
    float* w2s  = (float*)(smem + 98304);                     // [128][64]   32 KB
    float* lgs  = (float*)(smem + 32768);                     // 5*64*64 f32 80 KB

    const int t = threadIdx.x;
    const int w = t >> 6, lane = t & 63;
    const int l15 = lane & 15, l4 = lane >> 4;
    const int cg = w & 3, rg = w >> 2;       // col-quad / row-half per wave
    const int rowBase = blockIdx.x << 6;     // 64 rows/block

    // ================= phase 1: h = relu(x @ W1 + b1) =================
    const int am = t >> 3;              // A-stage row 0..63
    const int rem = t & 7;              // A-stage octet 0..7 (8 floats each)
    const int aDst = ((am << 3) + (rem ^ (am & 7))) << 3;

    f32x4 acc[2][2];
    #pragma unroll
    for (int mf = 0; mf < 2; ++mf)
        #pragma unroll
        for (int nf = 0; nf < 2; ++nf) {
            f32x4 z = {0.f, 0.f, 0.f, 0.f};
            acc[mf][nf] = z;
        }

    auto stageB = [&](int buf, int k0) {
        #pragma unroll
        for (int j = 0; j < 2; ++j) {
            int c = (j << 9) + t;                 // 0..1023
            int n = c >> 3;
            int cl = (c & 7) ^ (n & 7);
            const size_t go = (size_t)n * 4096 + k0 + (cl << 3);
            gl_lds16(w1h + go, sBh0 + (buf << 13) + (c << 3));
            gl_lds16(w1l + go, sBl0 + (buf << 13) + (c << 3));
        }
    };
    auto loadA0 = [&](int k0) {
        return *(const float4*)(x + ((size_t)(rowBase + am) << 12) + k0 + (rem << 3));
    };
    auto loadA1 = [&](int k0) {
        return *(const float4*)(x + ((size_t)(rowBase + am) << 12) + k0 + (rem << 3) + 4);
    };
    auto writeA = [&](int buf, float4 a0, float4 a1) {
        float av[8] = {a0.x, a0.y, a0.z, a0.w, a1.x, a1.y, a1.z, a1.w};
        short8 H, L;
        #pragma unroll
        for (int i = 0; i < 8; ++i) {
            unsigned short hi = f2bf(av[i]);
            H[i] = (short)hi;
            L[i] = (short)f2bf(av[i] - bf2f(hi));
        }
        *(short8*)(sAh0 + (buf << 12) + aDst) = H;
        *(short8*)(sAl0 + (buf << 12) + aDst) = L;
    };

    stageB(0, 0);
    writeA(0, loadA0(0), loadA1(0));
    __syncthreads();

    for (int it = 0; it < 64; ++it) {
        const int buf = it & 1;
        const bool pf = (it + 1 < 64);
        float4 aN0 = make_float4(0.f, 0.f, 0.f, 0.f);
        float4 aN1 = make_float4(0.f, 0.f, 0.f, 0.f);
        if (pf) {
            stageB(buf ^ 1, (it + 1) << 6);   // gl_lds issues, lands by barrier
            aN0 = loadA0((it + 1) << 6);      // issue x loads BEFORE compute
            aN1 = loadA1((it + 1) << 6);
        }
        #pragma unroll
        for (int ks = 0; ks < 2; ++ks) {
            short8 ah[2], al[2], bh[2], bl[2];
            #pragma unroll
            for (int mf = 0; mf < 2; ++mf) {
                int rm = (rg << 5) + (mf << 4) + l15;
                int pc = ((ks << 2) + l4) ^ (rm & 7);
                int o = ((rm << 3) + pc) << 3;
                ah[mf] = *(const short8*)(sAh0 + (buf << 12) + o);
                al[mf] = *(const short8*)(sAl0 + (buf << 12) + o);
            }
            #pragma unroll
            for (int nf = 0; nf < 2; ++nf) {
                int rn = (cg << 5) + (nf << 4) + l15;
                int pc = ((ks << 2) + l4) ^ (rn & 7);
                int o = ((rn << 3) + pc) << 3;
                bh[nf] = *(const short8*)(sBh0 + (buf << 13) + o);
                bl[nf] = *(const short8*)(sBl0 + (buf << 13) + o);
            }
            #pragma unroll
            for (int mf = 0; mf < 2; ++mf)
                #pragma unroll
                for (int nf = 0; nf < 2; ++nf) {
                    acc[mf][nf] = __builtin_amdgcn_mfma_f32_16x16x32_bf16(
                        ah[mf], bh[nf], acc[mf][nf], 0, 0, 0);
                    acc[mf][nf] = __builtin_amdgcn_mfma_f32_16x16x32_bf16(
                        ah[mf], bl[nf], acc[mf][nf], 0, 0, 0);
                    acc[mf][nf] = __builtin_amdgcn_mfma_f32_16x16x32_bf16(
                        al[mf], bh[nf], acc[mf][nf], 0, 0, 0);
                }
        }
        if (pf) writeA(buf ^ 1, aN0, aN1);    // convert+ds_write AFTER compute
        __syncthreads();
    }

    // epilogue: bias + relu -> LDS hbuf, XOR-swizzled ((r&7)<<2 on float col)
    {
        #pragma unroll
        for (int nf = 0; nf < 2; ++nf) {
            const int col = (cg << 5) + (nf << 4) + l15;
            const float bias = b1[col];
            #pragma unroll
            for (int mf = 0; mf < 2; ++mf) {
                const int rbase = (rg << 5) + (mf << 4) + (l4 << 2);
                #pragma unroll
                for (int rr = 0; rr < 4; ++rr) {
                    const int r = rbase + rr;
                    float v = acc[mf][nf][rr] + bias;
                    v = v > 0.f ? v : 0.f;
                    hbuf[r * 128 + (col ^ ((r & 7) << 2))] = v;
                }
            }
        }
    }
    __syncthreads();

    // ================= phase 2: logits, pure-LDS inner loop =================
    const int lr = t >> 3;               // local row 0..63
    const int eg = t & 7;                // expert group (8 experts)
    const int e0 = eg << 3;
    const int row = rowBase + lr;
    const int lsw = (lr & 7) << 2;

    float acc2[5][8];
    #pragma unroll
    for (int s = 0; s < 5; ++s)
        #pragma unroll
        for (int e = 0; e < 8; ++e) acc2[s][e] = 0.f;

    // stage hm[slot] = masked h for sample sidx (bulk, coalesced m1 stream)
    auto stage_hm = [&](int slot, int sidx) {
        #pragma unroll
        for (int j = 0; j < 4; ++j) {
            int q = t + (j << 9);            // 0..2047
            int r = q >> 5, kq = q & 31;
            float4 mu = *(const float4*)(m1 + (size_t)sidx * (B_ROWS * 128)
                                            + (((size_t)(rowBase + r)) << 7) + (kq << 2));
            int off = r * 128 + ((kq << 2) ^ ((r & 7) << 2));
            float4 h4 = *(const float4*)(hbuf + off);
            float4 hm4;
            hm4.x = (mu.x >= 0.3f) ? h4.x * SCALE : 0.f;
            hm4.y = (mu.y >= 0.3f) ? h4.y * SCALE : 0.f;
            hm4.z = (mu.z >= 0.3f) ? h4.z * SCALE : 0.f;
            hm4.w = (mu.w >= 0.3f) ? h4.w * SCALE : 0.f;
            *(float4*)(hmb + (slot << 13) + off) = hm4;
        }
    };

    // stage W2 (32 KB, contiguous copy) once
    #pragma unroll
    for (int j = 0; j < 4; ++j) {
        int q = t + (j << 9);                // 0..2047 float4s
        *(float4*)(w2s + (q << 2)) = *(const float4*)(w2 + (q << 2));
    }
    stage_hm(0, 0);
    stage_hm(1, 1);
    __syncthreads();

    for (int p = 0; p < 3; ++p) {
        const int s0 = p << 1;
        const int ns = (p == 2) ? 1 : 2;
        const float* hm0 = hmb + lr * 128;
        const float* hm1 = hmb + 8192 + lr * 128;
        for (int kq = 0; kq < 32; ++kq) {
            const int hoff = (kq << 2) ^ lsw;
            float4 a0 = *(const float4*)(hm0 + hoff);
            float ha[4] = {a0.x, a0.y, a0.z, a0.w};
            float w2v[4][8];
            #pragma unroll
            for (int kk = 0; kk < 4; ++kk) {
                float4 wa = *(const float4*)(w2s + (((kq << 2) + kk) << 6) + e0);
                float4 wb = *(const float4*)(w2s + (((kq << 2) + kk) << 6) + e0 + 4);
                w2v[kk][0] = wa.x; w2v[kk][1] = wa.y; w2v[kk][2] = wa.z; w2v[kk][3] = wa.w;
                w2v[kk][4] = wb.x; w2v[kk][5] = wb.y; w2v[kk][6] = wb.z; w2v[kk][7] = wb.w;
            }
            #pragma unroll
            for (int kk = 0; kk < 4; ++kk)       // k ascending per accumulator
                #pragma unroll
                for (int e = 0; e < 8; ++e)
                    acc2[s0][e] += ha[kk] * w2v[kk][e];
            if (ns == 2) {
                float4 a1 = *(const float4*)(hm1 + hoff);
                float hb[4] = {a1.x, a1.y, a1.z, a1.w};
                #pragma unroll
                for (int kk = 0; kk < 4; ++kk)
                    #pragma unroll
                    for (int e = 0; e < 8; ++e)
                        acc2[s0 + 1][e] += hb[kk] * w2v[kk][e];
            }
        }
        __syncthreads();                      // all reads of hm done
        if (p < 2) {
            stage_hm(0, (p << 1) + 2);
            if (p == 0) stage_hm(1, 3);
            __syncthreads();                  // hm ready for next pair
        }
    }

    // +b2, mask2*scale, park in lgs (aliases hmb/w2s; FMA done + barrier)
    {
        float4 ba = *(const float4*)(b2 + e0);
        float4 bb = *(const float4*)(b2 + e0 + 4);
        float bv[8] = {ba.x, ba.y, ba.z, ba.w, bb.x, bb.y, bb.z, bb.w};
        #pragma unroll
        for (int s = 0; s < 5; ++s) {
            const float* m2p = m2 + ((size_t)s * B_ROWS + row) * 64 + e0;
            float4 ma = *(const float4*)m2p;
            float4 mb = *(const float4*)(m2p + 4);
            float mk[8] = {ma.x, ma.y, ma.z, ma.w, mb.x, mb.y, mb.z, mb.w};
            float lv[8];
            #pragma unroll
            for (int e = 0; e < 8; ++e) {
                float v = acc2[s][e] + bv[e];
                lv[e] = (mk[e] >= 0.3f) ? v * SCALE : 0.f;
            }
            float* dst = lgs + ((s << 6) + lr) * 64 + e0;
            *(float4*)dst = make_float4(lv[0], lv[1], lv[2], lv[3]);
            *(float4*)(dst + 4) = make_float4(lv[4], lv[5], lv[6], lv[7]);
        }
    }
    __syncthreads();

    // ================= phase 3: stats, wave per 8 rows =================
    for (int r8 = 0; r8 < 8; ++r8) {
        const int r = (w << 3) + r8;
        float l[5], p[5];
        #pragma unroll
        for (int s = 0; s < 5; ++s)
            l[s] = lgs[((s << 6) + r) * 64 + lane];

        float ml = ((((l[0] + l[1]) + l[2]) + l[3]) + l[4]) / 5.0f;

        #pragma unroll
        for (int s = 0; s < 5; ++s) {
            float mx = wave_max(l[s]);
            float ev = expf(l[s] - mx);
            float sm = wave_sum(ev);
            p[s] = ev / sm;
        }

        float mx = wave_max(ml);
        float ev = expf(ml - mx);
        float sm = wave_sum(ev);
        float prob = ev / sm;

        float mean = ((((p[0] + p[1]) + p[2]) + p[3]) + p[4]) / 5.0f;
        float var = 0.f;
        #pragma unroll
        for (int s = 0; s < 5; ++s) { float d = p[s] - mean; var += d * d; }
        float sd = sqrtf(var * 0.25f);
        float unc = wave_sum(sd) / 64.0f;

        float pv = prob;
        float vv[4]; int vi[4];
        #pragma unroll
        for (int q = 0; q < 4; ++q) {
            float bvx = pv; int bi = lane;
            #pragma unroll
            for (int m = 1; m < 64; m <<= 1) {
                float ov = __shfl_xor(bvx, m, 64);
                int oi = __shfl_xor(bi, m, 64);
                if (ov > bvx || (ov == bvx && oi < bi)) { bvx = ov; bi = oi; }
            }
            vv[q] = bvx; vi[q] = bi;
            if (lane == bi) pv = -1.f;
        }

        if (lane == 0) {
            int grow = rowBase + r;
            bool ug = unc > 0.3f;
            float4 fi = make_float4((float)vi[0], (float)vi[1],
                                    ug ? (float)vi[2] : -1.f,
                                    ug ? (float)vi[3] : -1.f);
            *(float4*)(out + (size_t)grow * 4) = fi;
            float4 fp = make_float4(vv[0], vv[1],
                                    ug ? vv[2] : 0.f,
                                    ug ? vv[3] : 0.f);
            *(float4*)(out + 65536 + (size_t)grow * 4) = fp;
            out[131072 + grow] = unc;
        }
    }
}

extern "C" void kernel_launch(void* const* d_in, const int* in_sizes, int n_in,
                              void* d_out, int out_size, void* d_ws, size_t ws_size,
                              hipStream_t stream) {
    const float* x  = (const float*)d_in[0];
    const float* W1 = (const float*)d_in[1];
    const float* b1 = (const float*)d_in[2];
    const float* W2 = (const float*)d_in[3];
    const float* b2 = (const float*)d_in[4];
    const float* m1 = (const float*)d_in[5];
    const float* m2 = (const float*)d_in[6];
    float* out = (float*)d_out;
    char* ws = (char*)d_ws;

    unsigned short* w1h = (unsigned short*)ws;                // 1 MB
    unsigned short* w1l = (unsigned short*)(ws + (1 << 20));  // 1 MB

    k_prep <<<2048, 256, 0, stream>>>(W1, w1h, w1l);
    k_fused<<<256,  512, 0, stream>>>(x, w1h, w1l, b1, W2, b2, m1, m2, out);
}

// Round 7
// 483.063 us; speedup vs baseline: 1.0027x; 1.0027x over previous
//
#include <hip/hip_runtime.h>

typedef short short8 __attribute__((ext_vector_type(8)));
typedef float f32x4 __attribute__((ext_vector_type(4)));

#define B_ROWS 16384
#define SCALE 1.4285714285714286f   // f32 round of 1/0.7, same as np

__device__ __forceinline__ float bf2f(unsigned short u) {
    return __uint_as_float(((unsigned)u) << 16);
}
__device__ __forceinline__ unsigned short f2bf(float f) {
    unsigned u = __float_as_uint(f);
    u += 0x7fffu + ((u >> 16) & 1u);   // RNE
    return (unsigned short)(u >> 16);
}

__device__ __forceinline__ void gl_lds16(const void* g, void* l) {
    __builtin_amdgcn_global_load_lds(
        (const __attribute__((address_space(1))) unsigned int*)g,
        (__attribute__((address_space(3))) unsigned int*)l, 16, 0, 0);
}

__device__ __forceinline__ float wave_max(float v) {
    #pragma unroll
    for (int m = 1; m < 64; m <<= 1) v = fmaxf(v, __shfl_xor(v, m, 64));
    return v;
}
__device__ __forceinline__ float wave_sum(float v) {
    #pragma unroll
    for (int m = 1; m < 64; m <<= 1) v += __shfl_xor(v, m, 64);
    return v;
}

// ---- prep: W1 f32 (4096x128) -> transposed bf16 hi/lo splits (128x4096) ----
__global__ void k_prep(const float* __restrict__ w1,
                       unsigned short* __restrict__ w1h,
                       unsigned short* __restrict__ w1l) {
    int tid = blockIdx.x * 256 + threadIdx.x;     // 524288 total
    int n = tid >> 12, k = tid & 4095;
    float v = w1[k * 128 + n];
    unsigned short hi = f2bf(v);
    w1h[tid] = hi;
    w1l[tid] = f2bf(v - bf2f(hi));
}

// ---- GEMM1, deep-pipelined: h = relu(x @ W1 + b1) ----------------------
// M=64/block, 256 blocks (1/CU), 512 threads (8 waves, 2x4 wave tile grid).
// B (W1 splits): gl_lds staged 2 tiles ahead into a 3-buffer ring.
// A (x): global->reg prefetch 2 ahead (2 static sets), convert+ds_write 1
// ahead into 2-buffer sA. Loop barrier is raw s_barrier + lgkmcnt(0) only —
// NO vmcnt(0) drain; the writeA register-dependency wait (in-order vmcnt
// retirement) retires the 2-iteration-old gl_lds batch before each barrier.
// MFMA order identical to R5 -> bit-identical h.
struct A2 { float4 a, b; };

__global__ __launch_bounds__(512, 1) void k_gemm(
        const float* __restrict__ x,
        const unsigned short* __restrict__ w1h,
        const unsigned short* __restrict__ w1l,
        const float* __restrict__ b1,
        float* __restrict__ hout) {
    __shared__ __attribute__((aligned(128))) char smem[131072];
    unsigned short* sBh0 = (unsigned short*)smem;             // [3][128*64] 48K
    unsigned short* sBl0 = (unsigned short*)(smem + 49152);   // [3][128*64] 48K
    unsigned short* sAh0 = (unsigned short*)(smem + 98304);   // [2][64*64]  16K
    unsigned short* sAl0 = (unsigned short*)(smem + 114688);  // [2][64*64]  16K

    const int t = threadIdx.x;
    const int w = t >> 6, lane = t & 63;
    const int l15 = lane & 15, l4 = lane >> 4;
    const int cg = w & 3, rg = w >> 2;
    const int rowBase = blockIdx.x << 6;

    const int am = t >> 3;              // A-stage row 0..63
    const int rem = t & 7;              // A-stage octet
    const int aDst = ((am << 3) + (rem ^ (am & 7))) << 3;

    f32x4 acc[2][2];
    #pragma unroll
    for (int mf = 0; mf < 2; ++mf)
        #pragma unroll
        for (int nf = 0; nf < 2; ++nf) {
            f32x4 z = {0.f, 0.f, 0.f, 0.f};
            acc[mf][nf] = z;
        }

    auto stageB = [&](int bbuf, int k0) {
        #pragma unroll
        for (int j = 0; j < 2; ++j) {
            int c = (j << 9) + t;
            int n = c >> 3;
            int cl = (c & 7) ^ (n & 7);
            const size_t go = (size_t)n * 4096 + k0 + (cl << 3);
            gl_lds16(w1h + go, sBh0 + (bbuf << 13) + (c << 3));
            gl_lds16(w1l + go, sBl0 + (bbuf << 13) + (c << 3));
        }
    };
    auto loadA = [&](int k0) {
        const float* src = x + ((size_t)(rowBase + am) << 12) + k0 + (rem << 3);
        A2 r;
        r.a = *(const float4*)src;
        r.b = *(const float4*)(src + 4);
        return r;
    };
    auto writeA = [&](int abuf, A2 v) {
        float av[8] = {v.a.x, v.a.y, v.a.z, v.a.w, v.b.x, v.b.y, v.b.z, v.b.w};
        short8 H, L;
        #pragma unroll
        for (int i = 0; i < 8; ++i) {
            unsigned short hi = f2bf(av[i]);
            H[i] = (short)hi;
            L[i] = (short)f2bf(av[i] - bf2f(hi));
        }
        *(short8*)(sAh0 + (abuf << 12) + aDst) = H;
        *(short8*)(sAl0 + (abuf << 12) + aDst) = L;
    };
    auto compute = [&](int abuf, int bbuf) {
        #pragma unroll
        for (int ks = 0; ks < 2; ++ks) {
            short8 ah[2], al[2], bh[2], bl[2];
            #pragma unroll
            for (int mf = 0; mf < 2; ++mf) {
                int rm = (rg << 5) + (mf << 4) + l15;
                int pc = ((ks << 2) + l4) ^ (rm & 7);
                int o = ((rm << 3) + pc) << 3;
                ah[mf] = *(const short8*)(sAh0 + (abuf << 12) + o);
                al[mf] = *(const short8*)(sAl0 + (abuf << 12) + o);
            }
            #pragma unroll
            for (int nf = 0; nf < 2; ++nf) {
                int rn = (cg << 5) + (nf << 4) + l15;
                int pc = ((ks << 2) + l4) ^ (rn & 7);
                int o = ((rn << 3) + pc) << 3;
                bh[nf] = *(const short8*)(sBh0 + (bbuf << 13) + o);
                bl[nf] = *(const short8*)(sBl0 + (bbuf << 13) + o);
            }
            #pragma unroll
            for (int mf = 0; mf < 2; ++mf)
                #pragma unroll
                for (int nf = 0; nf < 2; ++nf) {
                    acc[mf][nf] = __builtin_amdgcn_mfma_f32_16x16x32_bf16(
                        ah[mf], bh[nf], acc[mf][nf], 0, 0, 0);
                    acc[mf][nf] = __builtin_amdgcn_mfma_f32_16x16x32_bf16(
                        ah[mf], bl[nf], acc[mf][nf], 0, 0, 0);
                    acc[mf][nf] = __builtin_amdgcn_mfma_f32_16x16x32_bf16(
                        al[mf], bh[nf], acc[mf][nf], 0, 0, 0);
                }
        }
    };
    #define SOFTBAR() do { \
        asm volatile("s_waitcnt lgkmcnt(0)" ::: "memory"); \
        __builtin_amdgcn_s_barrier(); } while (0)

    int rb0 = 0, rb1 = 1, rb2 = 2;   // rb0 = compute buf, rb2 = stage target
    // prologue: tiles 0,1 staged; A(0) written; A(1) in Q
    stageB(0, 0);
    stageB(1, 64);
    A2 P = loadA(0);
    A2 Q = loadA(64);
    writeA(0, P);
    __syncthreads();              // one full drain, prologue only

    for (int m = 0; m < 31; ++m) {
        const int kE = (2 * m + 2) << 6;
        const int kO = (2 * m + 3) << 6;
        // it = 2m (even): compute sA0 / sB rb0
        stageB(rb2, kE);
        P = loadA(kE);
        writeA(1, Q);             // waits Q -> 2-iter-old gl_lds retired
        compute(0, rb0);
        SOFTBAR();
        { int tb = rb0; rb0 = rb1; rb1 = rb2; rb2 = tb; }
        // it = 2m+1 (odd): compute sA1 / sB rb0
        stageB(rb2, kO);
        Q = loadA(kO);
        writeA(0, P);
        compute(1, rb0);
        SOFTBAR();
        { int tb = rb0; rb0 = rb1; rb1 = rb2; rb2 = tb; }
    }
    // it = 62
    writeA(1, Q);
    compute(0, rb0);
    SOFTBAR();
    { int tb = rb0; rb0 = rb1; rb1 = rb2; rb2 = tb; }
    // it = 63
    compute(1, rb0);

    // epilogue: bias + relu -> global h (f32)
    #pragma unroll
    for (int nf = 0; nf < 2; ++nf) {
        const int col = (cg << 5) + (nf << 4) + l15;
        const float bias = b1[col];
        #pragma unroll
        for (int mf = 0; mf < 2; ++mf) {
            const int rbase = (rg << 5) + (mf << 4) + (l4 << 2);
            #pragma unroll
            for (int rr = 0; rr < 4; ++rr) {
                const int r = rowBase + rbase + rr;
                float v = acc[mf][nf][rr] + bias;
                hout[(size_t)r * 128 + col] = v > 0.f ? v : 0.f;
            }
        }
    }
    #undef SOFTBAR
}

// ---- logits + stats (R4 structure, h from global) -----------------------
// M=32/block, 512 blocks, 512 threads. hm staged to LDS in bulk (coalesced
// m1+h streams), W2 in LDS once; FMA inner loop pure-LDS. Math == R4.
// LDS: hmb[2][32*128] @0 (32K), w2s[128*64] @32K (32K); lgs 40K aliases @0.
__global__ __launch_bounds__(512, 2) void k_logstats(
        const float* __restrict__ hg,
        const float* __restrict__ w2,
        const float* __restrict__ b2,
        const float* __restrict__ m1,
        const float* __restrict__ m2,
        float* __restrict__ out) {
    __shared__ __attribute__((aligned(128))) char smem[65536];
    float* hmb = (float*)smem;                 // [2][32*128] 32 KB
    float* w2s = (float*)(smem + 32768);       // [128][64]   32 KB
    float* lgs = (float*)smem;                 // 5*32*64 f32 40 KB (alias)

    const int t = threadIdx.x;
    const int w = t >> 6, lane = t & 63;
    const int lr = t >> 4;               // local row 0..31
    const int eg = t & 15;               // expert group (4 experts)
    const int e0 = eg << 2;
    const int rowBase = blockIdx.x << 5;
    const int row = rowBase + lr;
    const int lsw = (lr & 7) << 2;

    float acc2[5][4];
    #pragma unroll
    for (int s = 0; s < 5; ++s)
        #pragma unroll
        for (int e = 0; e < 4; ++e) acc2[s][e] = 0.f;

    auto stage_hm = [&](int slot, int sidx) {
        #pragma unroll
        for (int j = 0; j < 2; ++j) {
            int q = t + (j << 9);            // 0..1023
            int r = q >> 5, kq = q & 31;
            size_t gidx = ((size_t)(rowBase + r)) << 7;
            float4 mu = *(const float4*)(m1 + (size_t)sidx * (B_ROWS * 128)
                                            + gidx + (kq << 2));
            float4 h4 = *(const float4*)(hg + gidx + (kq << 2));
            float4 hm4;
            hm4.x = (mu.x >= 0.3f) ? h4.x * SCALE : 0.f;
            hm4.y = (mu.y >= 0.3f) ? h4.y * SCALE : 0.f;
            hm4.z = (mu.z >= 0.3f) ? h4.z * SCALE : 0.f;
            hm4.w = (mu.w >= 0.3f) ? h4.w * SCALE : 0.f;
            *(float4*)(hmb + (slot << 12) + r * 128 + ((kq << 2) ^ ((r & 7) << 2))) = hm4;
        }
    };

    // stage W2 (32 KB contiguous) once
    #pragma unroll
    for (int j = 0; j < 4; ++j) {
        int q = t + (j << 9);                // 0..2047 float4s
        *(float4*)(w2s + (q << 2)) = *(const float4*)(w2 + (q << 2));
    }
    stage_hm(0, 0);
    stage_hm(1, 1);
    __syncthreads();

    for (int p = 0; p < 3; ++p) {
        const int s0 = p << 1;
        const int ns = (p == 2) ? 1 : 2;
        const float* hm0 = hmb + lr * 128;
        const float* hm1 = hmb + 4096 + lr * 128;
        for (int kq = 0; kq < 32; ++kq) {
            const int hoff = (kq << 2) ^ lsw;
            float4 a0 = *(const float4*)(hm0 + hoff);
            float ha[4] = {a0.x, a0.y, a0.z, a0.w};
            float w2v[4][4];
            #pragma unroll
            for (int kk = 0; kk < 4; ++kk) {
                float4 wa = *(const float4*)(w2s + (((kq << 2) + kk) << 6) + e0);
                w2v[kk][0] = wa.x; w2v[kk][1] = wa.y; w2v[kk][2] = wa.z; w2v[kk][3] = wa.w;
            }
            #pragma unroll
            for (int kk = 0; kk < 4; ++kk)       // k ascending per accumulator
                #pragma unroll
                for (int e = 0; e < 4; ++e)
                    acc2[s0][e] += ha[kk] * w2v[kk][e];
            if (ns == 2) {
                float4 a1 = *(const float4*)(hm1 + hoff);
                float hb[4] = {a1.x, a1.y, a1.z, a1.w};
                #pragma unroll
                for (int kk = 0; kk < 4; ++kk)
                    #pragma unroll
                    for (int e = 0; e < 4; ++e)
                        acc2[s0 + 1][e] += hb[kk] * w2v[kk][e];
            }
        }
        __syncthreads();
        if (p < 2) {
            stage_hm(0, (p << 1) + 2);
            if (p == 0) stage_hm(1, 3);
            __syncthreads();
        }
    }

    // +b2, mask2*scale, park in lgs (aliases hmb/w2s head; reads done)
    {
        float4 ba = *(const float4*)(b2 + e0);
        float bv4[4] = {ba.x, ba.y, ba.z, ba.w};
        #pragma unroll
        for (int s = 0; s < 5; ++s) {
            const float* m2p = m2 + ((size_t)s * B_ROWS + row) * 64 + e0;
            float4 ma = *(const float4*)m2p;
            float mk[4] = {ma.x, ma.y, ma.z, ma.w};
            float lv[4];
            #pragma unroll
            for (int e = 0; e < 4; ++e) {
                float v = acc2[s][e] + bv4[e];
                lv[e] = (mk[e] >= 0.3f) ? v * SCALE : 0.f;
            }
            *(float4*)(lgs + ((s << 5) + lr) * 64 + e0) =
                make_float4(lv[0], lv[1], lv[2], lv[3]);
        }
    }
    __syncthreads();

    // stats: wave per 4 rows
    for (int r4 = 0; r4 < 4; ++r4) {
        const int r = (w << 2) + r4;
        float l[5], p[5];
        #pragma unroll
        for (int s = 0; s < 5; ++s)
            l[s] = lgs[((s << 5) + r) * 64 + lane];

        float ml = ((((l[0] + l[1]) + l[2]) + l[3]) + l[4]) / 5.0f;

        #pragma unroll
        for (int s = 0; s < 5; ++s) {
            float mx = wave_max(l[s]);
            float ev = expf(l[s] - mx);
            float sm = wave_sum(ev);
            p[s] = ev / sm;
        }

        float mx = wave_max(ml);
        float ev = expf(ml - mx);
        float sm = wave_sum(ev);
        float prob = ev / sm;

        float mean = ((((p[0] + p[1]) + p[2]) + p[3]) + p[4]) / 5.0f;
        float var = 0.f;
        #pragma unroll
        for (int s = 0; s < 5; ++s) { float d = p[s] - mean; var += d * d; }
        float sd = sqrtf(var * 0.25f);
        float unc = wave_sum(sd) / 64.0f;

        float pv = prob;
        float vv[4]; int vi[4];
        #pragma unroll
        for (int q = 0; q < 4; ++q) {
            float bvx = pv; int bi = lane;
            #pragma unroll
            for (int m = 1; m < 64; m <<= 1) {
                float ov = __shfl_xor(bvx, m, 64);
                int oi = __shfl_xor(bi, m, 64);
                if (ov > bvx || (ov == bvx && oi < bi)) { bvx = ov; bi = oi; }
            }
            vv[q] = bvx; vi[q] = bi;
            if (lane == bi) pv = -1.f;
        }

        if (lane == 0) {
            int grow = rowBase + r;
            bool ug = unc > 0.3f;
            float4 fi = make_float4((float)vi[0], (float)vi[1],
                                    ug ? (float)vi[2] : -1.f,
                                    ug ? (float)vi[3] : -1.f);
            *(float4*)(out + (size_t)grow * 4) = fi;
            float4 fp = make_float4(vv[0], vv[1],
                                    ug ? vv[2] : 0.f,
                                    ug ? vv[3] : 0.f);
            *(float4*)(out + 65536 + (size_t)grow * 4) = fp;
            out[131072 + grow] = unc;
        }
    }
}

extern "C" void kernel_launch(void* const* d_in, const int* in_sizes, int n_in,
                              void* d_out, int out_size, void* d_ws, size_t ws_size,
                              hipStream_t stream) {
    const float* x  = (const float*)d_in[0];
    const float* W1 = (const float*)d_in[1];
    const float* b1 = (const float*)d_in[2];
    const float* W2 = (const float*)d_in[3];
    const float* b2 = (const float*)d_in[4];
    const float* m1 = (const float*)d_in[5];
    const float* m2 = (const float*)d_in[6];
    float* out = (float*)d_out;
    char* ws = (char*)d_ws;

    unsigned short* w1h = (unsigned short*)ws;                // 1 MB
    unsigned short* w1l = (unsigned short*)(ws + (1 << 20));  // 1 MB
    float* h = (float*)(ws + (2 << 20));                      // 8 MB

    k_prep    <<<2048, 256, 0, stream>>>(W1, w1h, w1l);
    k_gemm    <<<256,  512, 0, stream>>>(x, w1h, w1l, b1, h);
    k_logstats<<<512,  512, 0, stream>>>(h, W2, b2, m1, m2, out);
}

// Round 8
// 471.720 us; speedup vs baseline: 1.0269x; 1.0240x over previous
//
#include <hip/hip_runtime.h>

typedef short short8 __attribute__((ext_vector_type(8)));
typedef float f32x4 __attribute__((ext_vector_type(4)));

#define B_ROWS 16384
#define SCALE 1.4285714285714286f   // f32 round of 1/0.7, same as np

__device__ __forceinline__ float bf2f(unsigned short u) {
    return __uint_as_float(((unsigned)u) << 16);
}
__device__ __forceinline__ unsigned short f2bf(float f) {
    unsigned u = __float_as_uint(f);
    u += 0x7fffu + ((u >> 16) & 1u);   // RNE
    return (unsigned short)(u >> 16);
}

__device__ __forceinline__ void gl_lds16(const void* g, void* l) {
    __builtin_amdgcn_global_load_lds(
        (const __attribute__((address_space(1))) unsigned int*)g,
        (__attribute__((address_space(3))) unsigned int*)l, 16, 0, 0);
}

__device__ __forceinline__ float wave_max(float v) {
    #pragma unroll
    for (int m = 1; m < 64; m <<= 1) v = fmaxf(v, __shfl_xor(v, m, 64));
    return v;
}
__device__ __forceinline__ float wave_sum(float v) {
    #pragma unroll
    for (int m = 1; m < 64; m <<= 1) v += __shfl_xor(v, m, 64);
    return v;
}

// ---- prep: W1 f32 (4096x128) -> transposed bf16 hi/lo splits (128x4096) ----
__global__ void k_prep(const float* __restrict__ w1,
                       unsigned short* __restrict__ w1h,
                       unsigned short* __restrict__ w1l) {
    int tid = blockIdx.x * 256 + threadIdx.x;     // 524288 total
    int n = tid >> 12, k = tid & 4095;
    float v = w1[k * 128 + n];
    unsigned short hi = f2bf(v);
    w1h[tid] = hi;
    w1l[tid] = f2bf(v - bf2f(hi));
}

// ---- GEMM1: h = relu(x @ W1 + b1) — x-fetch-pathology fix ---------------
// Theory: lockstep blocks all reading the same 256B k-slice at 16KB stride
// starve HBM channel parallelism + row buffers. Fix:
//  (1) per-block k-tile rotation rot = 4*(b&15): 16 concurrent k-phases.
//  (2) A loaded in 1KB-per-row groups of 4 tiles (8 float4/thread) into two
//      static register sets G/H (all slot indices compile-time).
// B: gl_lds 3-buffer ring staged 2 tiles ahead; counted vmcnt(12)/vmcnt(4)
// per step (exact issue counts), never vmcnt(0) in the loop.
// Per-acc MFMA pass order unchanged; k-order rotated (f32 ~1e-6 jitter).
struct Grp { float4 a0, a1, b0, b1, c0, c1, d0, d1; };

__global__ __launch_bounds__(512, 1) void k_gemm(
        const float* __restrict__ x,
        const unsigned short* __restrict__ w1h,
        const unsigned short* __restrict__ w1l,
        const float* __restrict__ b1,
        float* __restrict__ hout) {
    __shared__ __attribute__((aligned(128))) char smem[131072];
    unsigned short* sBh0 = (unsigned short*)smem;             // [3][128*64] 48K
    unsigned short* sBl0 = (unsigned short*)(smem + 49152);   // [3][128*64] 48K
    unsigned short* sAh0 = (unsigned short*)(smem + 98304);   // [2][64*64]  16K
    unsigned short* sAl0 = (unsigned short*)(smem + 114688);  // [2][64*64]  16K

    const int t = threadIdx.x;
    const int w = t >> 6, lane = t & 63;
    const int l15 = lane & 15, l4 = lane >> 4;
    const int cg = w & 3, rg = w >> 2;
    const int rowBase = blockIdx.x << 6;
    const int rot4 = blockIdx.x & 15;       // k-group rotation (16 phases)

    const int am = t >> 3;              // A row 0..63
    const int rem = t & 7;              // A octet 0..7
    const int aDst = ((am << 3) + (rem ^ (am & 7))) << 3;

    f32x4 acc[2][2];
    #pragma unroll
    for (int mf = 0; mf < 2; ++mf)
        #pragma unroll
        for (int nf = 0; nf < 2; ++nf) {
            f32x4 z = {0.f, 0.f, 0.f, 0.f};
            acc[mf][nf] = z;
        }

    auto stageB = [&](int bbuf, int T) {
        const int k0 = ((T + (rot4 << 2)) & 63) << 6;
        #pragma unroll
        for (int j = 0; j < 2; ++j) {
            int c = (j << 9) + t;
            int n = c >> 3;
            int cl = (c & 7) ^ (n & 7);
            const size_t go = (size_t)n * 4096 + k0 + (cl << 3);
            gl_lds16(w1h + go, sBh0 + (bbuf << 13) + (c << 3));
            gl_lds16(w1l + go, sBl0 + (bbuf << 13) + (c << 3));
        }
    };
    auto loadGroup = [&](int g) {
        const float* rp = x + ((size_t)(rowBase + am) << 12)
                            + (((g + rot4) & 15) << 8) + (rem << 3);
        Grp r;
        r.a0 = *(const float4*)(rp);       r.a1 = *(const float4*)(rp + 4);
        r.b0 = *(const float4*)(rp + 64);  r.b1 = *(const float4*)(rp + 68);
        r.c0 = *(const float4*)(rp + 128); r.c1 = *(const float4*)(rp + 132);
        r.d0 = *(const float4*)(rp + 192); r.d1 = *(const float4*)(rp + 196);
        return r;
    };
    auto writeA = [&](int abuf, float4 va, float4 vb) {
        float av[8] = {va.x, va.y, va.z, va.w, vb.x, vb.y, vb.z, vb.w};
        short8 Hh, Ll;
        #pragma unroll
        for (int i = 0; i < 8; ++i) {
            unsigned short hi = f2bf(av[i]);
            Hh[i] = (short)hi;
            Ll[i] = (short)f2bf(av[i] - bf2f(hi));
        }
        *(short8*)(sAh0 + (abuf << 12) + aDst) = Hh;
        *(short8*)(sAl0 + (abuf << 12) + aDst) = Ll;
    };
    auto compute = [&](int abuf, int bbuf) {
        #pragma unroll
        for (int ks = 0; ks < 2; ++ks) {
            short8 ah[2], al[2], bh[2], bl[2];
            #pragma unroll
            for (int mf = 0; mf < 2; ++mf) {
                int rm = (rg << 5) + (mf << 4) + l15;
                int pc = ((ks << 2) + l4) ^ (rm & 7);
                int o = ((rm << 3) + pc) << 3;
                ah[mf] = *(const short8*)(sAh0 + (abuf << 12) + o);
                al[mf] = *(const short8*)(sAl0 + (abuf << 12) + o);
            }
            #pragma unroll
            for (int nf = 0; nf < 2; ++nf) {
                int rn = (cg << 5) + (nf << 4) + l15;
                int pc = ((ks << 2) + l4) ^ (rn & 7);
                int o = ((rn << 3) + pc) << 3;
                bh[nf] = *(const short8*)(sBh0 + (bbuf << 13) + o);
                bl[nf] = *(const short8*)(sBl0 + (bbuf << 13) + o);
            }
            #pragma unroll
            for (int mf = 0; mf < 2; ++mf)
                #pragma unroll
                for (int nf = 0; nf < 2; ++nf) {
                    acc[mf][nf] = __builtin_amdgcn_mfma_f32_16x16x32_bf16(
                        ah[mf], bh[nf], acc[mf][nf], 0, 0, 0);
                    acc[mf][nf] = __builtin_amdgcn_mfma_f32_16x16x32_bf16(
                        ah[mf], bl[nf], acc[mf][nf], 0, 0, 0);
                    acc[mf][nf] = __builtin_amdgcn_mfma_f32_16x16x32_bf16(
                        al[mf], bh[nf], acc[mf][nf], 0, 0, 0);
                }
        }
    };
    #define VM12() asm volatile("s_waitcnt vmcnt(12)" ::: "memory")
    #define VM4()  asm volatile("s_waitcnt vmcnt(4)"  ::: "memory")
    #define SOFTBAR() do { \
        asm volatile("s_waitcnt lgkmcnt(0)" ::: "memory"); \
        __builtin_amdgcn_s_barrier(); } while (0)
    #define RINGROT() do { int tb = rb0; rb0 = rb1; rb1 = rb2; rb2 = tb; } while (0)

    int rb0 = 0, rb1 = 1, rb2 = 2;
    // prologue: B tiles 0,1 staged; G = group0; A tile0 written (reg-wait
    // on G retires both stageB batches); one barrier.
    stageB(0, 0);
    stageB(1, 1);
    Grp G = loadGroup(0);
    Grp H;
    writeA(0, G.a0, G.a1);
    SOFTBAR();

    for (int s8 = 0; s8 < 8; ++s8) {
        const int T0 = s8 << 3;
        // j=0: compute T0 (sA0), stage T0+2, load H = group 2*s8+1
        stageB(rb2, T0 + 2);
        H = loadGroup((T0 >> 2) + 1);
        writeA(1, G.b0, G.b1);          // tile T0+1
        VM12(); compute(0, rb0); SOFTBAR(); RINGROT();
        // j=1
        stageB(rb2, T0 + 3);
        writeA(0, G.c0, G.c1);          // tile T0+2
        VM12(); compute(1, rb0); SOFTBAR(); RINGROT();
        // j=2
        stageB(rb2, T0 + 4);
        writeA(1, G.d0, G.d1);          // tile T0+3
        VM4(); compute(0, rb0); SOFTBAR(); RINGROT();
        // j=3
        stageB(rb2, T0 + 5);
        writeA(0, H.a0, H.a1);          // tile T0+4
        VM4(); compute(1, rb0); SOFTBAR(); RINGROT();
        // j=4: load G = group 2*s8+2
        stageB(rb2, T0 + 6);
        G = loadGroup((T0 >> 2) + 2);
        writeA(1, H.b0, H.b1);          // tile T0+5
        VM12(); compute(0, rb0); SOFTBAR(); RINGROT();
        // j=5
        stageB(rb2, T0 + 7);
        writeA(0, H.c0, H.c1);          // tile T0+6
        VM12(); compute(1, rb0); SOFTBAR(); RINGROT();
        // j=6
        stageB(rb2, T0 + 8);
        writeA(1, H.d0, H.d1);          // tile T0+7
        VM4(); compute(0, rb0); SOFTBAR(); RINGROT();
        // j=7
        stageB(rb2, T0 + 9);
        writeA(0, G.a0, G.a1);          // tile T0+8 (s8=7: harmless garbage)
        VM4(); compute(1, rb0); SOFTBAR(); RINGROT();
    }

    // epilogue: bias + relu -> global h (f32)
    #pragma unroll
    for (int nf = 0; nf < 2; ++nf) {
        const int col = (cg << 5) + (nf << 4) + l15;
        const float bias = b1[col];
        #pragma unroll
        for (int mf = 0; mf < 2; ++mf) {
            const int rbase = (rg << 5) + (mf << 4) + (l4 << 2);
            #pragma unroll
            for (int rr = 0; rr < 4; ++rr) {
                const int r = rowBase + rbase + rr;
                float v = acc[mf][nf][rr] + bias;
                hout[(size_t)r * 128 + col] = v > 0.f ? v : 0.f;
            }
        }
    }
    #undef VM12
    #undef VM4
    #undef SOFTBAR
    #undef RINGROT
}

// ---- logits + stats (unchanged from R7) ---------------------------------
__global__ __launch_bounds__(512, 2) void k_logstats(
        const float* __restrict__ hg,
        const float* __restrict__ w2,
        const float* __restrict__ b2,
        const float* __restrict__ m1,
        const float* __restrict__ m2,
        float* __restrict__ out) {
    __shared__ __attribute__((aligned(128))) char smem[65536];
    float* hmb = (float*)smem;                 // [2][32*128] 32 KB
    float* w2s = (float*)(smem + 32768);       // [128][64]   32 KB
    float* lgs = (float*)smem;                 // 5*32*64 f32 40 KB (alias)

    const int t = threadIdx.x;
    const int w = t >> 6, lane = t & 63;
    const int lr = t >> 4;               // local row 0..31
    const int eg = t & 15;               // expert group (4 experts)
    const int e0 = eg << 2;
    const int rowBase = blockIdx.x << 5;
    const int row = rowBase + lr;
    const int lsw = (lr & 7) << 2;

    float acc2[5][4];
    #pragma unroll
    for (int s = 0; s < 5; ++s)
        #pragma unroll
        for (int e = 0; e < 4; ++e) acc2[s][e] = 0.f;

    auto stage_hm = [&](int slot, int sidx) {
        #pragma unroll
        for (int j = 0; j < 2; ++j) {
            int q = t + (j << 9);            // 0..1023
            int r = q >> 5, kq = q & 31;
            size_t gidx = ((size_t)(rowBase + r)) << 7;
            float4 mu = *(const float4*)(m1 + (size_t)sidx * (B_ROWS * 128)
                                            + gidx + (kq << 2));
            float4 h4 = *(const float4*)(hg + gidx + (kq << 2));
            float4 hm4;
            hm4.x = (mu.x >= 0.3f) ? h4.x * SCALE : 0.f;
            hm4.y = (mu.y >= 0.3f) ? h4.y * SCALE : 0.f;
            hm4.z = (mu.z >= 0.3f) ? h4.z * SCALE : 0.f;
            hm4.w = (mu.w >= 0.3f) ? h4.w * SCALE : 0.f;
            *(float4*)(hmb + (slot << 12) + r * 128 + ((kq << 2) ^ ((r & 7) << 2))) = hm4;
        }
    };

    #pragma unroll
    for (int j = 0; j < 4; ++j) {
        int q = t + (j << 9);                // 0..2047 float4s
        *(float4*)(w2s + (q << 2)) = *(const float4*)(w2 + (q << 2));
    }
    stage_hm(0, 0);
    stage_hm(1, 1);
    __syncthreads();

    for (int p = 0; p < 3; ++p) {
        const int s0 = p << 1;
        const int ns = (p == 2) ? 1 : 2;
        const float* hm0 = hmb + lr * 128;
        const float* hm1 = hmb + 4096 + lr * 128;
        for (int kq = 0; kq < 32; ++kq) {
            const int hoff = (kq << 2) ^ lsw;
            float4 a0 = *(const float4*)(hm0 + hoff);
            float ha[4] = {a0.x, a0.y, a0.z, a0.w};
            float w2v[4][4];
            #pragma unroll
            for (int kk = 0; kk < 4; ++kk) {
                float4 wa = *(const float4*)(w2s + (((kq << 2) + kk) << 6) + e0);
                w2v[kk][0] = wa.x; w2v[kk][1] = wa.y; w2v[kk][2] = wa.z; w2v[kk][3] = wa.w;
            }
            #pragma unroll
            for (int kk = 0; kk < 4; ++kk)       // k ascending per accumulator
                #pragma unroll
                for (int e = 0; e < 4; ++e)
                    acc2[s0][e] += ha[kk] * w2v[kk][e];
            if (ns == 2) {
                float4 a1 = *(const float4*)(hm1 + hoff);
                float hb[4] = {a1.x, a1.y, a1.z, a1.w};
                #pragma unroll
                for (int kk = 0; kk < 4; ++kk)
                    #pragma unroll
                    for (int e = 0; e < 4; ++e)
                        acc2[s0 + 1][e] += hb[kk] * w2v[kk][e];
            }
        }
        __syncthreads();
        if (p < 2) {
            stage_hm(0, (p << 1) + 2);
            if (p == 0) stage_hm(1, 3);
            __syncthreads();
        }
    }

    {
        float4 ba = *(const float4*)(b2 + e0);
        float bv4[4] = {ba.x, ba.y, ba.z, ba.w};
        #pragma unroll
        for (int s = 0; s < 5; ++s) {
            const float* m2p = m2 + ((size_t)s * B_ROWS + row) * 64 + e0;
            float4 ma = *(const float4*)m2p;
            float mk[4] = {ma.x, ma.y, ma.z, ma.w};
            float lv[4];
            #pragma unroll
            for (int e = 0; e < 4; ++e) {
                float v = acc2[s][e] + bv4[e];
                lv[e] = (mk[e] >= 0.3f) ? v * SCALE : 0.f;
            }
            *(float4*)(lgs + ((s << 5) + lr) * 64 + e0) =
                make_float4(lv[0], lv[1], lv[2], lv[3]);
        }
    }
    __syncthreads();

    for (int r4 = 0; r4 < 4; ++r4) {
        const int r = (w << 2) + r4;
        float l[5], p[5];
        #pragma unroll
        for (int s = 0; s < 5; ++s)
            l[s] = lgs[((s << 5) + r) * 64 + lane];

        float ml = ((((l[0] + l[1]) + l[2]) + l[3]) + l[4]) / 5.0f;

        #pragma unroll
        for (int s = 0; s < 5; ++s) {
            float mx = wave_max(l[s]);
            float ev = expf(l[s] - mx);
            float sm = wave_sum(ev);
            p[s] = ev / sm;
        }

        float mx = wave_max(ml);
        float ev = expf(ml - mx);
        float sm = wave_sum(ev);
        float prob = ev / sm;

        float mean = ((((p[0] + p[1]) + p[2]) + p[3]) + p[4]) / 5.0f;
        float var = 0.f;
        #pragma unroll
        for (int s = 0; s < 5; ++s) { float d = p[s] - mean; var += d * d; }
        float sd = sqrtf(var * 0.25f);
        float unc = wave_sum(sd) / 64.0f;

        float pv = prob;
        float vv[4]; int vi[4];
        #pragma unroll
        for (int q = 0; q < 4; ++q) {
            float bvx = pv; int bi = lane;
            #pragma unroll
            for (int m = 1; m < 64; m <<= 1) {
                float ov = __shfl_xor(bvx, m, 64);
                int oi = __shfl_xor(bi, m, 64);
                if (ov > bvx || (ov == bvx && oi < bi)) { bvx = ov; bi = oi; }
            }
            vv[q] = bvx; vi[q] = bi;
            if (lane == bi) pv = -1.f;
        }

        if (lane == 0) {
            int grow = rowBase + r;
            bool ug = unc > 0.3f;
            float4 fi = make_float4((float)vi[0], (float)vi[1],
                                    ug ? (float)vi[2] : -1.f,
                                    ug ? (float)vi[3] : -1.f);
            *(float4*)(out + (size_t)grow * 4) = fi;
            float4 fp = make_float4(vv[0], vv[1],
                                    ug ? vv[2] : 0.f,
                                    ug ? vv[3] : 0.f);
            *(float4*)(out + 65536 + (size_t)grow * 4) = fp;
            out[131072 + grow] = unc;
        }
    }
}

extern "C" void kernel_launch(void* const* d_in, const int* in_sizes, int n_in,
                              void* d_out, int out_size, void* d_ws, size_t ws_size,
                              hipStream_t stream) {
    const float* x  = (const float*)d_in[0];
    const float* W1 = (const float*)d_in[1];
    const float* b1 = (const float*)d_in[2];
    const float* W2 = (const float*)d_in[3];
    const float* b2 = (const float*)d_in[4];
    const float* m1 = (const float*)d_in[5];
    const float* m2 = (const float*)d_in[6];
    float* out = (float*)d_out;
    char* ws = (char*)d_ws;

    unsigned short* w1h = (unsigned short*)ws;                // 1 MB
    unsigned short* w1l = (unsigned short*)(ws + (1 << 20));  // 1 MB
    float* h = (float*)(ws + (2 << 20));                      // 8 MB

    k_prep    <<<2048, 256, 0, stream>>>(W1, w1h, w1l);
    k_gemm    <<<256,  512, 0, stream>>>(x, w1h, w1l, b1, h);
    k_logstats<<<512,  512, 0, stream>>>(h, W2, b2, m1, m2, out);
}